// Round 5
// baseline (1022.441 us; speedup 1.0000x reference)
//
#include <hip/hip_runtime.h>
#include <hip/hip_bf16.h>
#include <stdint.h>

#define B_ 4
#define S_ 2048
#define D_ 2048
#define NH_ 16
#define DH_ 128
#define M_ (B_ * S_)   // 8192

typedef __attribute__((ext_vector_type(8))) short short8;
typedef __attribute__((ext_vector_type(4))) float f32x4;
typedef __attribute__((ext_vector_type(4))) unsigned short u16x4;

__device__ __forceinline__ unsigned short bf16_rne(float f) {
  uint32_t u = __builtin_bit_cast(uint32_t, f);
  uint32_t r = (u + 0x7FFFu + ((u >> 16) & 1u)) >> 16;
  return (unsigned short)r;
}
__device__ __forceinline__ float bf16_f32(unsigned short h) {
  return __builtin_bit_cast(float, ((uint32_t)h) << 16);
}
__device__ __forceinline__ f32x4 mfma16(short8 a, short8 b, f32x4 c) {
  return __builtin_amdgcn_mfma_f32_16x16x32_bf16(a, b, c, 0, 0, 0);
}
// async global->LDS, 16B per lane. LDS dest must be linear (wave-uniform base + lane*16).
__device__ __forceinline__ void load_lds16(const void* g, void* l) {
  __builtin_amdgcn_global_load_lds((const __attribute__((address_space(1))) void*)g,
                                   (__attribute__((address_space(3))) void*)l,
                                   16, 0, 0);
}

// ---------------- elementwise ----------------
__global__ __launch_bounds__(256) void cast_bf16(const float* __restrict__ in,
                                                 unsigned short* __restrict__ out, int n4) {
  int i = blockIdx.x * 256 + threadIdx.x;
  if (i < n4) {
    f32x4 v = *(const f32x4*)(in + (size_t)i * 4);
    u16x4 o;
    for (int j = 0; j < 4; j++) o[j] = bf16_rne(v[j]);
    *(u16x4*)(out + (size_t)i * 4) = o;
  }
}

__global__ __launch_bounds__(256) void rope_tables(const int* __restrict__ tokpos,
                                                   float* __restrict__ cosT,
                                                   float* __restrict__ sinT) {
  int i = blockIdx.x * 256 + threadIdx.x;  // 0 .. 2048*64-1
  int s = i >> 6, f = i & 63;
  float pos = (float)tokpos[s];
  // theta^(-2f/128) = exp2(-f * (2/128) * log2(10000))
  float freq = exp2f((float)f * (-2.0f / 128.0f) * 13.287712379549449f);
  float ang = pos * freq;
  cosT[i] = cosf(ang);
  sinT[i] = sinf(ang);
}

// in-place RoPE on a bf16 [B*S, D] tensor (head-major cols). 8 elems (4 pairs) per thread.
__global__ __launch_bounds__(256) void rope_apply(unsigned short* __restrict__ X,
                                                  const float* __restrict__ cosT,
                                                  const float* __restrict__ sinT) {
  size_t i8 = ((size_t)blockIdx.x * 256 + threadIdx.x) * 8;
  int col = (int)(i8 & (D_ - 1));
  int s = (int)((i8 >> 11) & (S_ - 1));
  int d = col & (DH_ - 1);
  int p0 = d >> 1;  // pair index, multiple of 4
  short8 v = *(short8*)(X + i8);
  f32x4 cv = *(const f32x4*)(cosT + s * 64 + p0);
  f32x4 sv = *(const f32x4*)(sinT + s * 64 + p0);
  short8 o;
  for (int j = 0; j < 4; j++) {
    float xe = bf16_f32((unsigned short)v[2 * j]);
    float xo = bf16_f32((unsigned short)v[2 * j + 1]);
    float c = cv[j], sn = sv[j];
    o[2 * j] = (short)bf16_rne(c * xe - sn * xo);
    o[2 * j + 1] = (short)bf16_rne(sn * xe + c * xo);
  }
  *(short8*)(X + i8) = o;
}

// ---------------- GEMM: C[M,N] = A[M,K] * B[N,K]^T  (m97 structure) ----------------
// EPI 0: bf16 [M,N]; EPI 1: f32 [M,N]; EPI 2: bf16 transposed-per-head [B][H][dh][S]
template <int EPI>
__global__ __launch_bounds__(256) void gemm_bt(const unsigned short* __restrict__ A,
                                               const unsigned short* __restrict__ Bm,
                                               void* __restrict__ Cp, int M, int N, int K) {
  __shared__ short smA[128 * 32];
  __shared__ short smB[128 * 32];
  const int tid = threadIdx.x;
  const int lane = tid & 63, wv = tid >> 6;
  const int wm = wv >> 1, wn = wv & 1;
  const int lr = lane & 15, lg = lane >> 4;
  const int nwg = gridDim.x;
  const int wg = blockIdx.x;
  const int swz = (wg & 7) * (nwg >> 3) + (wg >> 3);  // bijective (nwg % 8 == 0)
  const int tiles_n = N >> 7;
  const int tm = swz / tiles_n, tn = swz % tiles_n;

  f32x4 acc[4][4] = {};

  for (int kt = 0; kt < K; kt += 32) {
    __syncthreads();
    for (int i = 0; i < 2; i++) {
      int c = tid + i * 256;           // chunk 0..511 (16B each)
      int row = c >> 2;                // tile row 0..127
      int cb = (c & 3) << 4;           // byte-in-row 0..63
      int cbs = cb ^ ((row & 3) << 4); // pre-swizzled global source (read applies same XOR)
      const char* asrc = (const char*)(A + (size_t)(tm * 128 + row) * K + kt) + cbs;
      load_lds16(asrc, (char*)smA + c * 16);
      const char* bsrc = (const char*)(Bm + (size_t)(tn * 128 + row) * K + kt) + cbs;
      load_lds16(bsrc, (char*)smB + c * 16);
    }
    __syncthreads();
    short8 af[4], bf[4];
    for (int i = 0; i < 4; i++) {
      int row = wm * 64 + i * 16 + lr;
      int rb = (lg * 16) ^ ((row & 3) << 4);
      af[i] = *(const short8*)((const char*)smA + row * 64 + rb);
    }
    for (int j = 0; j < 4; j++) {
      int row = wn * 64 + j * 16 + lr;
      int rb = (lg * 16) ^ ((row & 3) << 4);
      bf[j] = *(const short8*)((const char*)smB + row * 64 + rb);
    }
    for (int i = 0; i < 4; i++)
      for (int j = 0; j < 4; j++)
        acc[i][j] = mfma16(af[i], bf[j], acc[i][j]);
  }

  // epilogue; C/D layout: col = lane&15, row = (lane>>4)*4 + reg
  if (EPI == 0) {
    unsigned short* C = (unsigned short*)Cp;
    for (int i = 0; i < 4; i++) {
      int m0 = tm * 128 + wm * 64 + i * 16 + lg * 4;
      for (int j = 0; j < 4; j++) {
        int n = tn * 128 + wn * 64 + j * 16 + lr;
        for (int r = 0; r < 4; r++) C[(size_t)(m0 + r) * N + n] = bf16_rne(acc[i][j][r]);
      }
    }
  } else if (EPI == 1) {
    float* C = (float*)Cp;
    for (int i = 0; i < 4; i++) {
      int m0 = tm * 128 + wm * 64 + i * 16 + lg * 4;
      for (int j = 0; j < 4; j++) {
        int n = tn * 128 + wn * 64 + j * 16 + lr;
        for (int r = 0; r < 4; r++) C[(size_t)(m0 + r) * N + n] = acc[i][j][r];
      }
    }
  } else {
    // V^T layout: [B][NH][DH][S]; m -> (b, s), n -> (h, d); 4 consecutive s per lane -> 8B store
    unsigned short* C = (unsigned short*)Cp;
    for (int i = 0; i < 4; i++) {
      int m0 = tm * 128 + wm * 64 + i * 16 + lg * 4;
      int b = m0 >> 11, s0 = m0 & (S_ - 1);
      for (int j = 0; j < 4; j++) {
        int n = tn * 128 + wn * 64 + j * 16 + lr;
        int h = n >> 7, d = n & (DH_ - 1);
        u16x4 pk;
        for (int r = 0; r < 4; r++) pk[r] = bf16_rne(acc[i][j][r]);
        *(u16x4*)(C + (((size_t)(b * NH_ + h) * DH_ + d) * S_ + s0)) = pk;
      }
    }
  }
}

// ---------------- causal flash attention ----------------
// grid (S/64, B*NH); 4 waves, each wave owns 16 q rows. KVBLK=32.
#define KVBLK 32
__global__ __launch_bounds__(256) void attn_kernel(const unsigned short* __restrict__ Q,
                                                   const unsigned short* __restrict__ K,
                                                   const unsigned short* __restrict__ Vt,
                                                   unsigned short* __restrict__ O) {
  __shared__ short smK[KVBLK * DH_];   // [32][128] (XOR-swizzled rows, 256B)
  __shared__ short smV[DH_ * KVBLK];   // [128][32] (XOR-swizzled rows, 64B)
  __shared__ short smP[4 * 16 * KVBLK];

  const int tid = threadIdx.x;
  const int lane = tid & 63, w = tid >> 6;
  const int lr = lane & 15, lg = lane >> 4;
  const int qblk = gridDim.x - 1 - blockIdx.x;  // long-work blocks first
  const int bh = blockIdx.y;
  const int b = bh >> 4, h = bh & 15;
  const int q0 = qblk * 64;
  const int qw = q0 + w * 16;

  // Q fragments in registers: row = lr, k = ks*32 + lg*8 + j
  short8 qf[4];
  {
    const unsigned short* qrow = Q + ((size_t)(b * S_ + qw + lr)) * D_ + h * DH_ + lg * 8;
    for (int ks = 0; ks < 4; ks++) qf[ks] = *(const short8*)(qrow + ks * 32);
  }
  f32x4 Oacc[8] = {};
  float m_r[4], l_r[4];
  for (int r = 0; r < 4; r++) { m_r[r] = -1e30f; l_r[r] = 0.f; }

  const int kv_end = q0 + 64;
  const size_t kbase = (size_t)b * S_ * D_ + h * DH_;
  const size_t vbase = (size_t)(b * NH_ + h) * DH_ * S_;
  const float LOG2E = 1.4426950408889634f;
  const float scale = 0.08838834764831845f;  // 1/sqrt(128)

  for (int kv0 = 0; kv0 < kv_end; kv0 += KVBLK) {
    __syncthreads();
    for (int i = 0; i < 2; i++) {
      int c = tid + i * 256;
      // K tile: 32 rows x 256B
      int row = c >> 4;
      int cb = (c & 15) << 4;
      int cbs = cb ^ ((row & 7) << 4);
      const char* src = (const char*)(K + kbase + (size_t)(kv0 + row) * D_) + cbs;
      load_lds16(src, (char*)smK + c * 16);
      // Vt tile: 128 rows x 64B
      int rv = c >> 2;
      int cv = (c & 3) << 4;
      int cvs = cv ^ ((rv & 3) << 4);
      const char* srcv = (const char*)(Vt + vbase + (size_t)rv * S_ + kv0) + cvs;
      load_lds16(srcv, (char*)smV + c * 16);
    }
    __syncthreads();

    if (kv0 <= qw + 15) {  // wave has at least one unmasked row
      f32x4 sa[2] = {};
      for (int nt = 0; nt < 2; nt++) {
        int kv = nt * 16 + lr;
        for (int ks = 0; ks < 4; ks++) {
          int rb = (ks * 64 + lg * 16) ^ ((kv & 7) << 4);
          short8 kf = *(const short8*)((const char*)smK + kv * 256 + rb);
          sa[nt] = mfma16(qf[ks], kf, sa[nt]);
        }
      }
      const bool needmask = (kv0 + KVBLK - 1) > qw;
      float tmx[4];
      for (int r = 0; r < 4; r++) {
        float s0 = sa[0][r] * scale, s1 = sa[1][r] * scale;
        if (needmask) {
          int qg = qw + lg * 4 + r;
          if (kv0 + lr > qg) s0 = -1e30f;
          if (kv0 + 16 + lr > qg) s1 = -1e30f;
        }
        sa[0][r] = s0; sa[1][r] = s1;
        float t = fmaxf(s0, s1);
        t = fmaxf(t, __shfl_xor(t, 1));
        t = fmaxf(t, __shfl_xor(t, 2));
        t = fmaxf(t, __shfl_xor(t, 4));
        t = fmaxf(t, __shfl_xor(t, 8));
        tmx[r] = t;
      }
      float c_[4];
      for (int r = 0; r < 4; r++) {
        float mn = fmaxf(m_r[r], tmx[r]);
        c_[r] = exp2f((m_r[r] - mn) * LOG2E);
        float p0 = exp2f((sa[0][r] - mn) * LOG2E);
        float p1 = exp2f((sa[1][r] - mn) * LOG2E);
        sa[0][r] = p0; sa[1][r] = p1;
        float ps = p0 + p1;
        ps += __shfl_xor(ps, 1);
        ps += __shfl_xor(ps, 2);
        ps += __shfl_xor(ps, 4);
        ps += __shfl_xor(ps, 8);
        l_r[r] = l_r[r] * c_[r] + ps;
        m_r[r] = mn;
      }
      // P -> LDS (transpose lanes: acc row=(lg*4+r) -> A-frag row=lr)
      short* pw = smP + w * 16 * KVBLK;
      for (int nt = 0; nt < 2; nt++)
        for (int r = 0; r < 4; r++)
          pw[(lg * 4 + r) * KVBLK + nt * 16 + lr] = (short)bf16_rne(sa[nt][r]);
      for (int dt = 0; dt < 8; dt++)
        for (int r = 0; r < 4; r++) Oacc[dt][r] *= c_[r];
      short8 pf = *(const short8*)(pw + lr * KVBLK + lg * 8);
      for (int dt = 0; dt < 8; dt++) {
        int d = dt * 16 + lr;
        int rb = (lg * 16) ^ ((d & 3) << 4);
        short8 vf = *(const short8*)((const char*)smV + d * 64 + rb);
        Oacc[dt] = mfma16(pf, vf, Oacc[dt]);
      }
    }
  }

  for (int r = 0; r < 4; r++) {
    float inv = 1.0f / l_r[r];
    int qg = qw + lg * 4 + r;
    unsigned short* orow = O + ((size_t)(b * S_ + qg)) * D_ + h * DH_;
    for (int dt = 0; dt < 8; dt++) orow[dt * 16 + lr] = bf16_rne(Oacc[dt][r] * inv);
  }
}

// ---------------- launch ----------------
extern "C" void kernel_launch(void* const* d_in, const int* in_sizes, int n_in,
                              void* d_out, int out_size, void* d_ws, size_t ws_size,
                              hipStream_t stream) {
  const float* x = (const float*)d_in[0];
  const int* tokpos = (const int*)d_in[1];
  const float* Wq = (const float*)d_in[2];
  const float* Wk = (const float*)d_in[3];
  const float* Wv = (const float*)d_in[4];
  const float* Wo = (const float*)d_in[5];

  char* ws = (char*)d_ws;
  unsigned short* xb = (unsigned short*)(ws + 0);          // 33554432 B
  unsigned short* qb = (unsigned short*)(ws + 33554432);
  unsigned short* kb = (unsigned short*)(ws + 67108864);
  unsigned short* vtb = (unsigned short*)(ws + 100663296);
  unsigned short* ao = (unsigned short*)(ws + 134217728);
  unsigned short* wqb = (unsigned short*)(ws + 167772160); // 8388608 B each
  unsigned short* wkb = (unsigned short*)(ws + 176160768);
  unsigned short* wvb = (unsigned short*)(ws + 184549376);
  unsigned short* wob = (unsigned short*)(ws + 192937984);
  float* cosT = (float*)(ws + 201326592);                  // 524288 B
  float* sinT = (float*)(ws + 201850880);

  cast_bf16<<<16384, 256, 0, stream>>>(x, xb, 4194304);
  cast_bf16<<<4096, 256, 0, stream>>>(Wq, wqb, 1048576);
  cast_bf16<<<4096, 256, 0, stream>>>(Wk, wkb, 1048576);
  cast_bf16<<<4096, 256, 0, stream>>>(Wv, wvb, 1048576);
  cast_bf16<<<4096, 256, 0, stream>>>(Wo, wob, 1048576);
  rope_tables<<<512, 256, 0, stream>>>(tokpos, cosT, sinT);

  gemm_bt<0><<<1024, 256, 0, stream>>>(xb, wqb, qb, M_, D_, D_);
  gemm_bt<0><<<1024, 256, 0, stream>>>(xb, wkb, kb, M_, D_, D_);
  gemm_bt<2><<<1024, 256, 0, stream>>>(xb, wvb, vtb, M_, D_, D_);

  rope_apply<<<8192, 256, 0, stream>>>(qb, cosT, sinT);
  rope_apply<<<8192, 256, 0, stream>>>(kb, cosT, sinT);

  dim3 ag(S_ / 64, B_ * NH_);
  attn_kernel<<<ag, 256, 0, stream>>>(qb, kb, vtb, ao);

  gemm_bt<1><<<1024, 256, 0, stream>>>(ao, wob, (float*)d_out, M_, D_, D_);
}

// Round 11
// 809.959 us; speedup vs baseline: 1.2623x; 1.2623x over previous
//
#include <hip/hip_runtime.h>
#include <hip/hip_bf16.h>
#include <stdint.h>

#define B_ 4
#define S_ 2048
#define D_ 2048
#define NH_ 16
#define DH_ 128
#define M_ (B_ * S_)   // 8192

typedef __attribute__((ext_vector_type(8))) short short8;
typedef __attribute__((ext_vector_type(4))) short short4_t;
typedef __attribute__((ext_vector_type(4))) float f32x4;
typedef __attribute__((ext_vector_type(4))) unsigned short u16x4;

__device__ __forceinline__ unsigned short bf16_rne(float f) {
  uint32_t u = __builtin_bit_cast(uint32_t, f);
  uint32_t r = (u + 0x7FFFu + ((u >> 16) & 1u)) >> 16;
  return (unsigned short)r;
}
__device__ __forceinline__ float bf16_f32(unsigned short h) {
  return __builtin_bit_cast(float, ((uint32_t)h) << 16);
}
__device__ __forceinline__ f32x4 mfma16(short8 a, short8 b, f32x4 c) {
  return __builtin_amdgcn_mfma_f32_16x16x32_bf16(a, b, c, 0, 0, 0);
}
// async global->LDS, 16B per lane. LDS dest must be linear (wave-uniform base + lane*16).
__device__ __forceinline__ void load_lds16(const void* g, void* l) {
  __builtin_amdgcn_global_load_lds((const __attribute__((address_space(1))) void*)g,
                                   (__attribute__((address_space(3))) void*)l,
                                   16, 0, 0);
}

// ---------------- elementwise ----------------
__global__ __launch_bounds__(256) void cast_bf16(const float* __restrict__ in,
                                                 unsigned short* __restrict__ out, int n4) {
  int i = blockIdx.x * 256 + threadIdx.x;
  if (i < n4) {
    f32x4 v = *(const f32x4*)(in + (size_t)i * 4);
    u16x4 o;
    for (int j = 0; j < 4; j++) o[j] = bf16_rne(v[j]);
    *(u16x4*)(out + (size_t)i * 4) = o;
  }
}

__global__ __launch_bounds__(256) void rope_tables(const int* __restrict__ tokpos,
                                                   float* __restrict__ cosT,
                                                   float* __restrict__ sinT) {
  int i = blockIdx.x * 256 + threadIdx.x;  // 0 .. 2048*64-1
  int s = i >> 6, f = i & 63;
  float pos = (float)tokpos[s];
  float freq = exp2f((float)f * (-2.0f / 128.0f) * 13.287712379549449f);
  float ang = pos * freq;
  cosT[i] = cosf(ang);
  sinT[i] = sinf(ang);
}

// in-place RoPE on a bf16 [B*S, D] tensor (head-major cols). 8 elems (4 pairs) per thread.
__global__ __launch_bounds__(256) void rope_apply(unsigned short* __restrict__ X,
                                                  const float* __restrict__ cosT,
                                                  const float* __restrict__ sinT) {
  size_t i8 = ((size_t)blockIdx.x * 256 + threadIdx.x) * 8;
  int col = (int)(i8 & (D_ - 1));
  int s = (int)((i8 >> 11) & (S_ - 1));
  int d = col & (DH_ - 1);
  int p0 = d >> 1;  // pair index, multiple of 4
  short8 v = *(short8*)(X + i8);
  f32x4 cv = *(const f32x4*)(cosT + s * 64 + p0);
  f32x4 sv = *(const f32x4*)(sinT + s * 64 + p0);
  short8 o;
  for (int j = 0; j < 4; j++) {
    float xe = bf16_f32((unsigned short)v[2 * j]);
    float xo = bf16_f32((unsigned short)v[2 * j + 1]);
    float c = cv[j], sn = sv[j];
    o[2 * j] = (short)bf16_rne(c * xe - sn * xo);
    o[2 * j + 1] = (short)bf16_rne(sn * xe + c * xo);
  }
  *(short8*)(X + i8) = o;
}

// ---------------- GEMM: C[M,N] = A[M,K] * B[N,K]^T  (m97 structure) ----------------
// EPI 0: bf16 [M,N]; EPI 1: f32 [M,N]; EPI 2: bf16 transposed-per-head [B][H][dh][S]
template <int EPI>
__global__ __launch_bounds__(256) void gemm_bt(const unsigned short* __restrict__ A,
                                               const unsigned short* __restrict__ Bm,
                                               void* __restrict__ Cp, int M, int N, int K) {
  __shared__ short smA[128 * 32];
  __shared__ short smB[128 * 32];
  const int tid = threadIdx.x;
  const int lane = tid & 63, wv = tid >> 6;
  const int wm = wv >> 1, wn = wv & 1;
  const int lr = lane & 15, lg = lane >> 4;
  const int nwg = gridDim.x;
  const int wg = blockIdx.x;
  const int swz = (wg & 7) * (nwg >> 3) + (wg >> 3);  // bijective (nwg % 8 == 0)
  const int tiles_n = N >> 7;
  const int tm = swz / tiles_n, tn = swz % tiles_n;

  f32x4 acc[4][4] = {};

  for (int kt = 0; kt < K; kt += 32) {
    __syncthreads();
    for (int i = 0; i < 2; i++) {
      int c = tid + i * 256;           // chunk 0..511 (16B each)
      int row = c >> 2;                // tile row 0..127
      int cb = (c & 3) << 4;           // byte-in-row 0..63
      int cbs = cb ^ ((row & 3) << 4); // pre-swizzled global source (read applies same XOR)
      const char* asrc = (const char*)(A + (size_t)(tm * 128 + row) * K + kt) + cbs;
      load_lds16(asrc, (char*)smA + c * 16);
      const char* bsrc = (const char*)(Bm + (size_t)(tn * 128 + row) * K + kt) + cbs;
      load_lds16(bsrc, (char*)smB + c * 16);
    }
    __syncthreads();
    short8 af[4], bf[4];
    for (int i = 0; i < 4; i++) {
      int row = wm * 64 + i * 16 + lr;
      int rb = (lg * 16) ^ ((row & 3) << 4);
      af[i] = *(const short8*)((const char*)smA + row * 64 + rb);
    }
    for (int j = 0; j < 4; j++) {
      int row = wn * 64 + j * 16 + lr;
      int rb = (lg * 16) ^ ((row & 3) << 4);
      bf[j] = *(const short8*)((const char*)smB + row * 64 + rb);
    }
    for (int i = 0; i < 4; i++)
      for (int j = 0; j < 4; j++)
        acc[i][j] = mfma16(af[i], bf[j], acc[i][j]);
  }

  // epilogue; C/D layout: col = lane&15, row = (lane>>4)*4 + reg
  if (EPI == 0) {
    unsigned short* C = (unsigned short*)Cp;
    for (int i = 0; i < 4; i++) {
      int m0 = tm * 128 + wm * 64 + i * 16 + lg * 4;
      for (int j = 0; j < 4; j++) {
        int n = tn * 128 + wn * 64 + j * 16 + lr;
        for (int r = 0; r < 4; r++) C[(size_t)(m0 + r) * N + n] = bf16_rne(acc[i][j][r]);
      }
    }
  } else if (EPI == 1) {
    float* C = (float*)Cp;
    for (int i = 0; i < 4; i++) {
      int m0 = tm * 128 + wm * 64 + i * 16 + lg * 4;
      for (int j = 0; j < 4; j++) {
        int n = tn * 128 + wn * 64 + j * 16 + lr;
        for (int r = 0; r < 4; r++) C[(size_t)(m0 + r) * N + n] = acc[i][j][r];
      }
    }
  } else {
    // V^T layout: [B][NH][DH][S]; m -> (b, s), n -> (h, d); 4 consecutive s per lane -> 8B store
    unsigned short* C = (unsigned short*)Cp;
    for (int i = 0; i < 4; i++) {
      int m0 = tm * 128 + wm * 64 + i * 16 + lg * 4;
      int b = m0 >> 11, s0 = m0 & (S_ - 1);
      for (int j = 0; j < 4; j++) {
        int n = tn * 128 + wn * 64 + j * 16 + lr;
        int h = n >> 7, d = n & (DH_ - 1);
        u16x4 pk;
        for (int r = 0; r < 4; r++) pk[r] = bf16_rne(acc[i][j][r]);
        *(u16x4*)(C + (((size_t)(b * NH_ + h) * DH_ + d) * S_ + s0)) = pk;
      }
    }
  }
}

// ---------------- causal flash attention ----------------
// grid (B*NH, S/128); 8 waves x 16 q-rows = 128 q/block. KVB=32, double-buffered
// K/V with stage-ahead: stage(t+1) -> compute(t) -> vmcnt(0)+barrier (T3-minimum).
#define KVB 32
__global__ __launch_bounds__(512) void attn_kernel(const unsigned short* __restrict__ Q,
                                                   const unsigned short* __restrict__ K,
                                                   const unsigned short* __restrict__ Vt,
                                                   unsigned short* __restrict__ O) {
  __shared__ short smK[2][KVB * DH_];  // [32][128] rows (256B), XOR-swz (row&7)<<4
  __shared__ short smV[2][DH_ * KVB];  // [128][32] rows (64B),  XOR-swz (row&3)<<4
  __shared__ short smP[8][16 * 36];    // per-wave P, stride 36 shorts (conflict-free)

  const int tid = threadIdx.x;
  const int lane = tid & 63, w = tid >> 6;  // 8 waves
  const int lr = lane & 15, lg = lane >> 4;
  const int bh = blockIdx.x;                       // x = head for XCD L2 locality
  const int qblk = gridDim.y - 1 - blockIdx.y;     // long-work blocks first
  const int b = bh >> 4, h = bh & 15;
  const int q0 = qblk * 128;
  const int qw = q0 + w * 16;

  // Q fragments in registers: row = lr, k = ks*32 + lg*8 + j
  short8 qf[4];
  {
    const unsigned short* qrow = Q + ((size_t)(b * S_ + qw + lr)) * D_ + h * DH_ + lg * 8;
    for (int ks = 0; ks < 4; ks++) qf[ks] = *(const short8*)(qrow + ks * 32);
  }
  f32x4 Oacc[8] = {};
  float m_r[4], l_r[4];
  for (int r = 0; r < 4; r++) { m_r[r] = -1e30f; l_r[r] = 0.f; }

  const int ntile = (q0 + 128) / KVB;
  const size_t kbase = (size_t)b * S_ * D_ + h * DH_;
  const size_t vbase = (size_t)(b * NH_ + h) * DH_ * S_;
  const float LOG2E = 1.4426950408889634f;
  const float scale = 0.08838834764831845f;  // 1/sqrt(128)
  short* pw = smP[w];

  // stage tile t into buffer buf: 512 threads x (1 K chunk + 1 V chunk) of 16B
  auto stage = [&](int t, int buf) {
    int c = tid;
    {  // K tile: 32 rows x 256B
      int row = c >> 4, cb = (c & 15) << 4;
      int cbs = cb ^ ((row & 7) << 4);
      const char* src = (const char*)(K + kbase + (size_t)(t * KVB + row) * D_) + cbs;
      load_lds16(src, (char*)smK[buf] + c * 16);
    }
    {  // Vt tile: 128 rows x 64B
      int rv = c >> 2, cv = (c & 3) << 4;
      int cvs = cv ^ ((rv & 3) << 4);
      const char* srcv = (const char*)(Vt + vbase + (size_t)rv * S_ + t * KVB) + cvs;
      load_lds16(srcv, (char*)smV[buf] + c * 16);
    }
  };

  stage(0, 0);
  for (int t = 0; t < ntile; ++t) {
    const int cur = t & 1;
    asm volatile("s_waitcnt vmcnt(0)" ::: "memory");  // stage(t) landed (per-wave)
    __syncthreads();                                   // all waves: tile t ready, buf cur^1 free
    if (t + 1 < ntile) stage(t + 1, cur ^ 1);          // prefetch overlaps compute below
    const int kv0 = t * KVB;

    if (kv0 <= qw + 15) {  // wave has at least one unmasked row
      f32x4 sa[2] = {};
      for (int nt = 0; nt < 2; nt++) {
        int kv = nt * 16 + lr;
        for (int ks = 0; ks < 4; ks++) {
          int rb = (ks * 64 + lg * 16) ^ ((kv & 7) << 4);
          short8 kf = *(const short8*)((const char*)smK[cur] + kv * 256 + rb);
          sa[nt] = mfma16(qf[ks], kf, sa[nt]);
        }
      }
      const bool needmask = (kv0 + KVB - 1) > qw;
      float tmx[4];
      for (int r = 0; r < 4; r++) {
        float s0 = sa[0][r] * scale, s1 = sa[1][r] * scale;
        if (needmask) {
          int qg = qw + lg * 4 + r;
          if (kv0 + lr > qg) s0 = -1e30f;
          if (kv0 + 16 + lr > qg) s1 = -1e30f;
        }
        sa[0][r] = s0; sa[1][r] = s1;
        float tv = fmaxf(s0, s1);
        tv = fmaxf(tv, __shfl_xor(tv, 1));
        tv = fmaxf(tv, __shfl_xor(tv, 2));
        tv = fmaxf(tv, __shfl_xor(tv, 4));
        tv = fmaxf(tv, __shfl_xor(tv, 8));
        tmx[r] = tv;
      }
      // THR=0 defer-rescale: exact; skips rescale when no row max grew
      bool grew = (tmx[0] > m_r[0]) | (tmx[1] > m_r[1]) | (tmx[2] > m_r[2]) | (tmx[3] > m_r[3]);
      if (__any(grew)) {
        for (int r = 0; r < 4; r++) {
          float mn = fmaxf(m_r[r], tmx[r]);
          float c_ = exp2f((m_r[r] - mn) * LOG2E);
          m_r[r] = mn;
          l_r[r] *= c_;
          for (int dt = 0; dt < 8; dt++) Oacc[dt][r] *= c_;
        }
      }
      // P = exp(s - m), truncated to bf16 consistently for both l-sum and PV
      for (int r = 0; r < 4; r++) {
        float p0 = exp2f((sa[0][r] - m_r[r]) * LOG2E);
        float p1 = exp2f((sa[1][r] - m_r[r]) * LOG2E);
        uint32_t u0 = __builtin_bit_cast(uint32_t, p0) & 0xFFFF0000u;
        uint32_t u1 = __builtin_bit_cast(uint32_t, p1) & 0xFFFF0000u;
        float ps = __builtin_bit_cast(float, u0) + __builtin_bit_cast(float, u1);
        ps += __shfl_xor(ps, 1);
        ps += __shfl_xor(ps, 2);
        ps += __shfl_xor(ps, 4);
        ps += __shfl_xor(ps, 8);
        l_r[r] += ps;
        int rho = (lg * 4 + r) * 36;
        pw[rho + lr] = (short)(u0 >> 16);
        pw[rho + 16 + lr] = (short)(u1 >> 16);
      }
      // PV: A-frag of P (row=lr, k=lg*8+j) via two conflict-free b64 reads
      union S8 { short8 v; short4_t h[2]; } pu;
      const short* pp = pw + lr * 36 + lg * 8;
      pu.h[0] = *(const short4_t*)pp;
      pu.h[1] = *(const short4_t*)(pp + 4);
      short8 pf = pu.v;
      for (int dt = 0; dt < 8; dt++) {
        int d = dt * 16 + lr;
        int rb = (lg * 16) ^ ((d & 3) << 4);
        short8 vf = *(const short8*)((const char*)smV[cur] + d * 64 + rb);
        Oacc[dt] = mfma16(pf, vf, Oacc[dt]);
      }
    }
  }

  for (int r = 0; r < 4; r++) {
    float inv = 1.0f / l_r[r];
    int qg = qw + lg * 4 + r;
    unsigned short* orow = O + ((size_t)(b * S_ + qg)) * D_ + h * DH_;
    for (int dt = 0; dt < 8; dt++) orow[dt * 16 + lr] = bf16_rne(Oacc[dt][r] * inv);
  }
}

// ---------------- launch ----------------
extern "C" void kernel_launch(void* const* d_in, const int* in_sizes, int n_in,
                              void* d_out, int out_size, void* d_ws, size_t ws_size,
                              hipStream_t stream) {
  const float* x = (const float*)d_in[0];
  const int* tokpos = (const int*)d_in[1];
  const float* Wq = (const float*)d_in[2];
  const float* Wk = (const float*)d_in[3];
  const float* Wv = (const float*)d_in[4];
  const float* Wo = (const float*)d_in[5];

  char* ws = (char*)d_ws;
  unsigned short* xb = (unsigned short*)(ws + 0);          // 33554432 B
  unsigned short* qb = (unsigned short*)(ws + 33554432);
  unsigned short* kb = (unsigned short*)(ws + 67108864);
  unsigned short* vtb = (unsigned short*)(ws + 100663296);
  unsigned short* ao = (unsigned short*)(ws + 134217728);
  unsigned short* wqb = (unsigned short*)(ws + 167772160); // 8388608 B each
  unsigned short* wkb = (unsigned short*)(ws + 176160768);
  unsigned short* wvb = (unsigned short*)(ws + 184549376);
  unsigned short* wob = (unsigned short*)(ws + 192937984);
  float* cosT = (float*)(ws + 201326592);                  // 524288 B
  float* sinT = (float*)(ws + 201850880);

  cast_bf16<<<16384, 256, 0, stream>>>(x, xb, 4194304);
  cast_bf16<<<4096, 256, 0, stream>>>(Wq, wqb, 1048576);
  cast_bf16<<<4096, 256, 0, stream>>>(Wk, wkb, 1048576);
  cast_bf16<<<4096, 256, 0, stream>>>(Wv, wvb, 1048576);
  cast_bf16<<<4096, 256, 0, stream>>>(Wo, wob, 1048576);
  rope_tables<<<512, 256, 0, stream>>>(tokpos, cosT, sinT);

  gemm_bt<0><<<1024, 256, 0, stream>>>(xb, wqb, qb, M_, D_, D_);
  gemm_bt<0><<<1024, 256, 0, stream>>>(xb, wkb, kb, M_, D_, D_);
  gemm_bt<2><<<1024, 256, 0, stream>>>(xb, wvb, vtb, M_, D_, D_);

  rope_apply<<<8192, 256, 0, stream>>>(qb, cosT, sinT);
  rope_apply<<<8192, 256, 0, stream>>>(kb, cosT, sinT);

  dim3 ag(B_ * NH_, S_ / 128);
  attn_kernel<<<ag, 512, 0, stream>>>(qb, kb, vtb, ao);

  gemm_bt<1><<<1024, 256, 0, stream>>>(ao, wob, (float*)d_out, M_, D_, D_);
}